// Round 11
// baseline (214.102 us; speedup 1.0000x reference)
//
#include <hip/hip_runtime.h>

// CausalSelfAttention: B=2, T=2048, C=1024, H=16, D=64
// bf16 MFMA; BK=64 XOR-swizzled GEMMs, register-prefetch double-buffering.
// gemm_qkv: x fp32->bf16 converted INLINE in A register-staging.
// gemm_out: split-K combine (o0+o1)/l fused INLINE in A register-staging.
// S^T-form flash attention, fixed-C softmax, 2-way split-K, K/V dbuf via Q-alias.
// 4 dispatches: cvt_w -> gemm_qkv -> attn -> gemm_out.
// NOTES: __launch_bounds__(256,4) spills acc (R6). Per-lane register A-frags
// w/o LDS regressed (R8). LDS-path fused combine regressed (R7).
#define BSZ 2
#define SEQ 2048
#define NEMBD 1024
#define NHEAD 16
#define HDIM 64
#define BT (BSZ * SEQ)          // 4096
#define QKV_LD (3 * NEMBD)      // 3072
#define SCALE_LOG2E 0.1803368665f   // (1/sqrt(64)) * log2(e)

typedef unsigned short u16;
typedef __attribute__((ext_vector_type(8))) short short8;     // 8 bf16 (MFMA A/B frag)
typedef __attribute__((ext_vector_type(4))) float floatx4;    // MFMA C/D frag
typedef __attribute__((ext_vector_type(4))) unsigned short ushort4v;

#define MFMA16(a, b, c) __builtin_amdgcn_mfma_f32_16x16x32_bf16(a, b, c, 0, 0, 0)

__device__ __forceinline__ void gload_lds16(const void* g, void* l) {
  __builtin_amdgcn_global_load_lds(
      (const __attribute__((address_space(1))) unsigned int*)(g),
      (__attribute__((address_space(3))) unsigned int*)(l), 16, 0, 0);
}

__device__ __forceinline__ u16 f2bf(float f) {  // fp32 -> bf16 RNE
  unsigned int u = __builtin_bit_cast(unsigned int, f);
  u += 0x7FFFu + ((u >> 16) & 1u);
  return (u16)(u >> 16);
}

__device__ __forceinline__ float bf2f(u16 v) {
  return __builtin_bit_cast(float, (unsigned)v << 16);
}

// ---------------------------------------------------------------------------
// fp32->bf16 conversion of w_attn + w_proj (weights only; x is inline now).
// ---------------------------------------------------------------------------
#define N_WA (QKV_LD * NEMBD)      // 3145728
#define N_WP (NEMBD * NEMBD)       // 1048576
__global__ __launch_bounds__(256) void cvt_w(const float* __restrict__ wa,
                                             const float* __restrict__ wp,
                                             u16* __restrict__ wab,
                                             u16* __restrict__ wpb) {
  int i = (blockIdx.x * 256 + threadIdx.x) * 8;
  const float* src;
  u16* dst;
  if (i < N_WA) { src = wa + i;          dst = wab + i; }
  else          { src = wp + (i - N_WA); dst = wpb + (i - N_WA); }
  float4 a = *(const float4*)(src);
  float4 b = *(const float4*)(src + 4);
  short8 o;
  o[0] = (short)f2bf(a.x); o[1] = (short)f2bf(a.y);
  o[2] = (short)f2bf(a.z); o[3] = (short)f2bf(a.w);
  o[4] = (short)f2bf(b.x); o[5] = (short)f2bf(b.y);
  o[6] = (short)f2bf(b.z); o[7] = (short)f2bf(b.w);
  *(short8*)(dst) = o;
}

// ---------------------------------------------------------------------------
// GEMM1: qkv = x @ w_attn^T. 128x128 tile, BK=64, XOR-swizzled LDS.
// Register-prefetch dbuf; A = x read as fp32 (2x float4/lane) and converted
// to bf16 at ds_write time (cvt kernel for x eliminated).
// n0 < 2048 (Q,K): operand-SWAPPED MFMA -> lane packs 4 consecutive n.
// n0 >= 2048 (V): normal order -> lane packs 4 consecutive tokens -> vtg.
// ---------------------------------------------------------------------------
__global__ __launch_bounds__(256) void gemm_qkv(const float* __restrict__ X,
                                                const u16* __restrict__ B,
                                                u16* __restrict__ qkb,
                                                u16* __restrict__ vtg) {
  __shared__ __align__(16) u16 As[128 * 64];  // 16 KB
  __shared__ __align__(16) u16 Bs[128 * 64];  // 16 KB
  const int t = threadIdx.x;
  const int lane = t & 63, w = t >> 6;
  const int l15 = lane & 15, quad = lane >> 4;
  const int wm = w >> 1, wn = w & 1;
  const int m0 = blockIdx.y * 128, n0 = blockIdx.x * 128;
  const int is_v = (n0 >= 2 * NEMBD);

  const int srow8 = t >> 3;
  const int kc = (t & 7) ^ (srow8 & 7);
  const float* gA = X + (size_t)(m0 + srow8) * NEMBD + kc * 8;
  const u16*   gB = B + (size_t)(n0 + srow8) * NEMBD + kc * 8;

  floatx4 acc[4][4] = {};
  float4 rax[4][2];
  short8 rb[4];

#define QKV_LOAD(K0)                                                           \
  { _Pragma("unroll")                                                          \
    for (int is = 0; is < 4; ++is) {                                           \
      rax[is][0] = *(const float4*)(gA + (size_t)(is * 32) * NEMBD + (K0));    \
      rax[is][1] = *(const float4*)(gA + (size_t)(is * 32) * NEMBD + (K0) + 4);\
      rb[is]     = *(const short8*)(gB + (size_t)(is * 32) * NEMBD + (K0));    \
    } }
#define QKV_WRITE()                                                            \
  { _Pragma("unroll")                                                          \
    for (int is = 0; is < 4; ++is) {                                           \
      short8 v;                                                                \
      v[0] = (short)f2bf(rax[is][0].x); v[1] = (short)f2bf(rax[is][0].y);      \
      v[2] = (short)f2bf(rax[is][0].z); v[3] = (short)f2bf(rax[is][0].w);      \
      v[4] = (short)f2bf(rax[is][1].x); v[5] = (short)f2bf(rax[is][1].y);      \
      v[6] = (short)f2bf(rax[is][1].z); v[7] = (short)f2bf(rax[is][1].w);      \
      *(short8*)&As[(is * 256 + t) * 8] = v;                                   \
      *(short8*)&Bs[(is * 256 + t) * 8] = rb[is];                              \
    } }

  QKV_LOAD(0);
  QKV_WRITE();
  __syncthreads();

  for (int k0 = 0; k0 < NEMBD; k0 += 64) {
    const int more = (k0 + 64 < NEMBD);
    if (more) QKV_LOAD(k0 + 64);   // latency overlaps the MFMA phase below
#pragma unroll
    for (int kh = 0; kh < 2; ++kh) {
      short8 af[4], bfr[4];
#pragma unroll
      for (int mt = 0; mt < 4; ++mt) {
        int row = wm * 64 + mt * 16 + l15;
        af[mt] = *(const short8*)&As[row * 64 + (((kh * 4 + quad) ^ (row & 7)) * 8)];
      }
#pragma unroll
      for (int nt = 0; nt < 4; ++nt) {
        int row = wn * 64 + nt * 16 + l15;
        bfr[nt] = *(const short8*)&Bs[row * 64 + (((kh * 4 + quad) ^ (row & 7)) * 8)];
      }
      if (is_v) {
#pragma unroll
        for (int mt = 0; mt < 4; ++mt)
#pragma unroll
          for (int nt = 0; nt < 4; ++nt)
            acc[mt][nt] = MFMA16(af[mt], bfr[nt], acc[mt][nt]);   // D[m][n]
      } else {
#pragma unroll
        for (int mt = 0; mt < 4; ++mt)
#pragma unroll
          for (int nt = 0; nt < 4; ++nt)
            acc[mt][nt] = MFMA16(bfr[nt], af[mt], acc[mt][nt]);   // D[n][m]
      }
    }
    __syncthreads();               // all waves done reading tile k0
    if (more) {
      QKV_WRITE();                 // vmcnt wait here (loads had full compute to land)
      __syncthreads();             // tile k0+64 visible (lgkm-only drain)
    }
  }
#undef QKV_LOAD
#undef QKV_WRITE

  if (is_v) {
#pragma unroll
    for (int mt = 0; mt < 4; ++mt)
#pragma unroll
      for (int nt = 0; nt < 4; ++nt) {
        int hd = n0 + wn * 64 + nt * 16 + l15 - 2 * NEMBD;
        int token = m0 + wm * 64 + mt * 16 + quad * 4;
        int b = token >> 11, tp = token & (SEQ - 1);
        ushort4v pk;
#pragma unroll
        for (int r = 0; r < 4; ++r) pk[r] = f2bf(acc[mt][nt][r]);
        *(ushort4v*)&vtg[((size_t)(b * NEMBD + hd)) * SEQ + tp] = pk;
      }
  } else {
#pragma unroll
    for (int mt = 0; mt < 4; ++mt) {
      size_t token = (size_t)(m0 + wm * 64 + mt * 16 + l15);
#pragma unroll
      for (int nt = 0; nt < 4; ++nt) {
        int nc = n0 + wn * 64 + nt * 16 + quad * 4;
        ushort4v pk;
#pragma unroll
        for (int r = 0; r < 4; ++r) pk[r] = f2bf(acc[mt][nt][r]);
        *(ushort4v*)&qkb[token * 2048 + nc] = pk;
      }
    }
  }
}

// ---------------------------------------------------------------------------
// Flash attention (causal), S^T form, fixed-C softmax (C=8), 2-way split-K.
// K/V double-buffered (buf1 aliases dead Q tile) -> 1 barrier per K-tile.
// ---------------------------------------------------------------------------
__global__ __launch_bounds__(256) void attn_mfma4(const u16* __restrict__ qkb,
                                                  const u16* __restrict__ vtg,
                                                  u16* __restrict__ opart,
                                                  float* __restrict__ lpart) {
  const int bx = blockIdx.x;
  const int qt = 15 - (bx >> 6);
  const int r6 = bx & 63;
  const int bh = r6 >> 1, half = r6 & 1;
  const int b = bh >> 4, h = bh & 15;
  const int t = threadIdx.x, lane = t & 63, w = t >> 6;
  const int l15 = lane & 15, quad = lane >> 4;

  __shared__ __align__(16) u16 S[25600];  // 50 KB
  u16* Qs  = S;           // 128x64 swizzled (prologue only; becomes KV buf1)
  u16* KV0 = S + 8192;    // Ks @ +0 (64x64), Vt @ +4096 (64x64)
  u16* KV1 = S;           // aliases Qs
  u16* Pa  = S + 16384;   // 128x72

  const int kt0 = half ? (qt + 1) : 0;
  const int nkt = qt + 1;

  // ---- stage Q ----
  {
    const u16* qb = qkb + ((size_t)(b * SEQ + qt * 128)) * 2048 + h * HDIM;
#pragma unroll
    for (int is = 0; is < 4; ++is) {
      int s = is * 256 + t;
      int row = s >> 3, pos = s & 7;
      int kc = pos ^ (row & 7);
      gload_lds16(qb + (size_t)row * 2048 + kc * 8, &Qs[s * 8]);
    }
  }

#define STAGE_KV(KT, BUF)                                                      \
  {                                                                            \
    const u16* kb_ = qkb + ((size_t)(b * SEQ + (KT) * 64)) * 2048 + NEMBD + h * HDIM; \
    const u16* vb_ = vtg + ((size_t)(bh * 64)) * SEQ + (KT) * 64;              \
    _Pragma("unroll")                                                          \
    for (int is = 0; is < 2; ++is) {                                           \
      int s = is * 256 + t;                                                    \
      int row = s >> 3, pos = s & 7;                                           \
      int kc = pos ^ (row & 7);                                                \
      gload_lds16(kb_ + (size_t)row * 2048 + kc * 8, &(BUF)[s * 8]);           \
      gload_lds16(vb_ + (size_t)row * SEQ + kc * 8, &(BUF)[4096 + s * 8]);     \
    }                                                                          \
  }

  STAGE_KV(kt0, KV0);
  __syncthreads();  // Q + kt0 staged

  short8 qf[2][2];
#pragma unroll
  for (int qs = 0; qs < 2; ++qs) {
    int qrow = w * 32 + qs * 16 + l15;
#pragma unroll
    for (int hf = 0; hf < 2; ++hf)
      qf[qs][hf] = *(const short8*)&Qs[qrow * 64 + (((hf * 4 + quad) ^ (qrow & 7)) * 8)];
  }
  __syncthreads();  // all qf reads done before KV1(=Qs) is overwritten

  float rs[2] = {0.f, 0.f};
  floatx4 o_acc[2][4] = {};

#define COMPUTE_TILE(BUF, KT, MASKED)                                          \
  {                                                                            \
    floatx4 sacc[2][4];                                                        \
    _Pragma("unroll")                                                          \
    for (int nt = 0; nt < 4; ++nt) {                                           \
      int krow = nt * 16 + l15;                                                \
      short8 kf0 = *(const short8*)&(BUF)[krow * 64 + ((quad ^ (krow & 7)) * 8)]; \
      short8 kf1 = *(const short8*)&(BUF)[krow * 64 + (((4 + quad) ^ (krow & 7)) * 8)]; \
      _Pragma("unroll")                                                        \
      for (int qs = 0; qs < 2; ++qs) {                                         \
        floatx4 z = {0.f, 0.f, 0.f, 0.f};                                      \
        z = MFMA16(kf0, qf[qs][0], z);                                         \
        z = MFMA16(kf1, qf[qs][1], z);                                         \
        sacc[qs][nt] = z;                                                      \
      }                                                                        \
    }                                                                          \
    _Pragma("unroll")                                                          \
    for (int qs = 0; qs < 2; ++qs) {                                           \
      const int qg = qt * 128 + w * 32 + qs * 16 + l15;                        \
      const int kb0 = (KT) * 64 + quad * 4;                                    \
      _Pragma("unroll")                                                        \
      for (int nt = 0; nt < 4; ++nt) {                                         \
        ushort4v pk;                                                           \
        _Pragma("unroll")                                                      \
        for (int r = 0; r < 4; ++r) {                                          \
          float p = exp2f(fmaf(sacc[qs][nt][r], SCALE_LOG2E, -8.0f));          \
          if (MASKED && (kb0 + nt * 16 + r) > qg) p = 0.0f;                    \
          rs[qs] += p;                                                         \
          pk[r] = f2bf(p);                                                     \
        }                                                                      \
        *(ushort4v*)&Pa[(w * 32 + qs * 16 + l15) * 72 + nt * 16 + quad * 4] = pk; \
      }                                                                        \
    }                                                                          \
    short8 pf[2][2];                                                           \
    _Pragma("unroll")                                                          \
    for (int qs = 0; qs < 2; ++qs) {                                           \
      const int prow = w * 32 + qs * 16 + l15;                                 \
      pf[qs][0] = *(const short8*)&Pa[prow * 72 + quad * 8];                   \
      pf[qs][1] = *(const short8*)&Pa[prow * 72 + 32 + quad * 8];              \
    }                                                                          \
    _Pragma("unroll")                                                          \
    for (int nt = 0; nt < 4; ++nt) {                                           \
      int drow = nt * 16 + l15;                                                \
      short8 vf0 = *(const short8*)&(BUF)[4096 + drow * 64 + ((quad ^ (drow & 7)) * 8)]; \
      short8 vf1 = *(const short8*)&(BUF)[4096 + drow * 64 + (((4 + quad) ^ (drow & 7)) * 8)]; \
      _Pragma("unroll")                                                        \
      for (int qs = 0; qs < 2; ++qs) {                                         \
        o_acc[qs][nt] = MFMA16(pf[qs][0], vf0, o_acc[qs][nt]);                 \
        o_acc[qs][nt] = MFMA16(pf[qs][1], vf1, o_acc[qs][nt]);                 \
      }                                                                        \
    }                                                                          \
  }

  for (int i = 0; i < nkt; ++i) {
    const int kt = kt0 + i;
    u16* cur = (i & 1) ? KV1 : KV0;
    u16* nxt = (i & 1) ? KV0 : KV1;
    if (i + 1 < nkt) STAGE_KV(kt0 + i + 1, nxt);   // async; drained at iter-end barrier
    if (kt >= 2 * qt) { COMPUTE_TILE(cur, kt, 1); }
    else              { COMPUTE_TILE(cur, kt, 0); }
    __syncthreads();  // single barrier: next staging visible + cur reads done
  }
#undef COMPUTE_TILE
#undef STAGE_KV

  // ---- epilogue: reduce l over quads, store partials ----
#pragma unroll
  for (int qs = 0; qs < 2; ++qs) {
    rs[qs] += __shfl_xor(rs[qs], 16, 64);
    rs[qs] += __shfl_xor(rs[qs], 32, 64);
    if (quad == 0)
      lpart[((size_t)half * 32 + bh) * SEQ + qt * 128 + w * 32 + qs * 16 + l15] = rs[qs];
  }
  u16* ob = opart + (size_t)half * BT * NEMBD;
#pragma unroll
  for (int qs = 0; qs < 2; ++qs)
#pragma unroll
    for (int nt = 0; nt < 4; ++nt)
#pragma unroll
      for (int r = 0; r < 4; ++r) {
        size_t tok = (size_t)(b * SEQ + qt * 128 + w * 32 + qs * 16 + quad * 4 + r);
        ob[tok * NEMBD + h * HDIM + nt * 16 + l15] = f2bf(o_acc[qs][nt][r]);
      }
}

// ---------------------------------------------------------------------------
// GEMM2 (+fused split-K combine): out(fp32) = ((O0+O1)/l) @ w_proj^T.
// 128x64 tile, BK=64 swizzled, register-prefetch dbuf (gemm_qkv's structure):
// o0/o1/lpart loaded into registers during compute of tile k, combined at
// ds_write time. Operand-swapped -> float4 stores. 512 blocks.
// ---------------------------------------------------------------------------
__global__ __launch_bounds__(256) void gemm_out(const u16* __restrict__ opart,
                                                const float* __restrict__ lpart,
                                                const u16* __restrict__ B,
                                                float* __restrict__ C) {
  __shared__ __align__(16) u16 As[128 * 64];  // 16 KB
  __shared__ __align__(16) u16 Bs[64 * 64];   //  8 KB
  const int t = threadIdx.x;
  const int lane = t & 63, w = t >> 6;
  const int l15 = lane & 15, quad = lane >> 4;
  const int wm = w >> 1, wn = w & 1;
  const int m0 = blockIdx.y * 128, n0 = blockIdx.x * 64;

  const int srow8 = t >> 3;
  const int kc = (t & 7) ^ (srow8 & 7);
  const u16* gO0 = opart + (size_t)(m0 + srow8) * NEMBD + kc * 8;
  const u16* gO1 = gO0 + (size_t)BT * NEMBD;
  const u16* gB  = B + (size_t)(n0 + srow8) * NEMBD + kc * 8;
  // lpart row indices for this thread's 4 A-rows (token = m0 + is*32 + srow8)
  const int tokb = (m0 + srow8) >> 11;          // batch (constant: m0 128-aligned, srow8<32... safe: is*32 keeps same batch within 128-row tile)
  const int tokq0 = (m0 + srow8) & (SEQ - 1);

  floatx4 acc[4][2] = {};
  short8 ro0[4], ro1[4], rb[2];
  float rl0[4], rl1[4];

#define OUT_LOAD(K0)                                                           \
  { const int h_ = (K0) >> 6;                                                  \
    _Pragma("unroll")                                                          \
    for (int is = 0; is < 4; ++is) {                                           \
      ro0[is] = *(const short8*)(gO0 + (size_t)(is * 32) * NEMBD + (K0));      \
      ro1[is] = *(const short8*)(gO1 + (size_t)(is * 32) * NEMBD + (K0));      \
      rl0[is] = lpart[(size_t)(tokb * 16 + h_) * SEQ + tokq0 + is * 32];       \
      rl1[is] = lpart[(size_t)(32 + tokb * 16 + h_) * SEQ + tokq0 + is * 32];  \
    }                                                                          \
    _Pragma("unroll")                                                          \
    for (int is = 0; is < 2; ++is)                                             \
      rb[is] = *(const short8*)(gB + (size_t)(is * 32) * NEMBD + (K0)); }
#define OUT_WRITE()                                                            \
  { _Pragma("unroll")                                                          \
    for (int is = 0; is < 4; ++is) {                                           \
      float inv = 1.0f / (rl0[is] + rl1[is]);                                  \
      short8 v;                                                                \
      _Pragma("unroll")                                                        \
      for (int j = 0; j < 8; ++j)                                              \
        v[j] = (short)f2bf((bf2f((u16)ro0[is][j]) + bf2f((u16)ro1[is][j])) * inv); \
      *(short8*)&As[(is * 256 + t) * 8] = v;                                   \
    }                                                                          \
    _Pragma("unroll")                                                          \
    for (int is = 0; is < 2; ++is)                                             \
      *(short8*)&Bs[(is * 256 + t) * 8] = rb[is]; }

  OUT_LOAD(0);
  OUT_WRITE();
  __syncthreads();

  for (int k0 = 0; k0 < NEMBD; k0 += 64) {
    const int more = (k0 + 64 < NEMBD);
    if (more) OUT_LOAD(k0 + 64);
#pragma unroll
    for (int kh = 0; kh < 2; ++kh) {
      short8 af[4], bfr[2];
#pragma unroll
      for (int mt = 0; mt < 4; ++mt) {
        int row = wm * 64 + mt * 16 + l15;
        af[mt] = *(const short8*)&As[row * 64 + (((kh * 4 + quad) ^ (row & 7)) * 8)];
      }
#pragma unroll
      for (int nt = 0; nt < 2; ++nt) {
        int row = wn * 32 + nt * 16 + l15;
        bfr[nt] = *(const short8*)&Bs[row * 64 + (((kh * 4 + quad) ^ (row & 7)) * 8)];
      }
#pragma unroll
      for (int mt = 0; mt < 4; ++mt)
#pragma unroll
        for (int nt = 0; nt < 2; ++nt)
          acc[mt][nt] = MFMA16(bfr[nt], af[mt], acc[mt][nt]);   // D[n][m]
    }
    __syncthreads();
    if (more) {
      OUT_WRITE();
      __syncthreads();
    }
  }
#undef OUT_LOAD
#undef OUT_WRITE

  // swapped: rows = n (quad*4+r), cols = token (l15) -> float4 stores
#pragma unroll
  for (int mt = 0; mt < 4; ++mt) {
    size_t token = (size_t)(m0 + wm * 64 + mt * 16 + l15);
#pragma unroll
    for (int nt = 0; nt < 2; ++nt) {
      int nc = n0 + wn * 32 + nt * 16 + quad * 4;
      float4 v = make_float4(acc[mt][nt][0], acc[mt][nt][1],
                             acc[mt][nt][2], acc[mt][nt][3]);
      *(float4*)&C[token * NEMBD + nc] = v;
    }
  }
}

// ---------------------------------------------------------------------------
extern "C" void kernel_launch(void* const* d_in, const int* in_sizes, int n_in,
                              void* d_out, int out_size, void* d_ws, size_t ws_size,
                              hipStream_t stream) {
  const float* x      = (const float*)d_in[0];
  const float* w_attn = (const float*)d_in[1];
  const float* w_proj = (const float*)d_in[2];
  float* out = (float*)d_out;

  // Workspace (u16 units), ~51 MB. No xb (x converted inline), no yb (combine
  // fused into gemm_out).
  u16* base  = (u16*)d_ws;
  u16* opart = base;                          // 2*4096*1024 = 8388608 u16
  u16* wab   = base + 8388608;                // 3145728 u16
  u16* wpb   = base + 11534336;               // 1048576 u16
  u16* qkb   = base + 12582912;               // 8388608 u16
  u16* vtg   = base + 20971520;               // 4194304 u16
  float* lpart = (float*)(base + 25165824);   // 2*32*2048 fp32

  cvt_w<<<(N_WA + N_WP) / 2048, 256, 0, stream>>>(w_attn, w_proj, wab, wpb);

  gemm_qkv<<<dim3(QKV_LD / 128, BT / 128), 256, 0, stream>>>(x, wab, qkb, vtg);

  attn_mfma4<<<dim3((SEQ / 128) * BSZ * NHEAD * 2), 256, 0, stream>>>(qkb, vtg, opart, lpart);

  gemm_out<<<dim3(NEMBD / 64, BT / 128), 256, 0, stream>>>(opart, lpart, wpb, out);
}